// Round 1
// baseline (107.383 us; speedup 1.0000x reference)
//
#include <hip/hip_runtime.h>
#include <hip/hip_bf16.h>
#include <cmath>

typedef unsigned short u16;
typedef __attribute__((ext_vector_type(8))) short short8v;
typedef __attribute__((ext_vector_type(8))) unsigned short ushort8v;
typedef __attribute__((ext_vector_type(4))) float f32x4;

#define NPIX 784      // 28*28
#define KP   800      // padded K (25 k-frags of 32)
#define NH   800      // HID
#define NROWS 32768

__device__ __forceinline__ u16 f2bf(float f) {
    union { float f; unsigned int u; } v; v.f = f;
    unsigned int u = v.u;
    unsigned int r = (u + 0x7FFFu + ((u >> 16) & 1u)) >> 16;   // RNE
    return (u16)r;
}

// ---------------------------------------------------------------------------
// Kernel 1: kre = Re(ifft2(ifftshift(tmask))), separable 28-pt DFT, 1 block.
// Also sets flag = 1.0 if kre is (numerically) a delta -> conv is identity.
// ---------------------------------------------------------------------------
__global__ void k_kre(const float* __restrict__ MRE, const float* __restrict__ MIM,
                      float* __restrict__ KRE, float* __restrict__ FLAG)
{
    __shared__ float msre[784], msim[784], tre[784], tim[784];
    __shared__ float c28[28], s28[28];
    __shared__ int smax;

    const int t = threadIdx.x;   // blockDim = 832
    if (t < 28) {
        float th = (float)t * (6.283185307179586f / 28.0f);
        s28[t] = sinf(th);
        c28[t] = cosf(th);
    }
    if (t == 0) smax = 0;
    if (t < 784) {
        int r = t / 28, c = t - r * 28;
        int idx = ((r + 14) % 28) * 28 + ((c + 14) % 28);   // ifftshift
        msre[t] = MRE[idx];
        msim[t] = MIM[idx];
    }
    __syncthreads();
    // pass 1 over columns: tmp[u][cc] = sum_v ms[u][v] * e^{+2pi i v cc/28}
    if (t < 784) {
        int u = t / 28, cc = t - u * 28;
        float re = 0.f, im = 0.f;
        int ph = 0;
        for (int v = 0; v < 28; ++v) {
            float cr = c28[ph], ci = s28[ph];
            float ar = msre[u * 28 + v], ai = msim[u * 28 + v];
            re += ar * cr - ai * ci;
            im += ar * ci + ai * cr;
            ph += cc; if (ph >= 28) ph -= 28;
        }
        tre[t] = re; tim[t] = im;
    }
    __syncthreads();
    // pass 2 over rows: kre[pr][pc] = (1/784) Re sum_u tmp[u][pc] e^{+2pi i u pr/28}
    float dev = 0.f;
    if (t < 784) {
        int pr = t / 28, pc = t - pr * 28;
        float s = 0.f;
        int ph = 0;
        for (int u = 0; u < 28; ++u) {
            s += tre[u * 28 + pc] * c28[ph] - tim[u * 28 + pc] * s28[ph];
            ph += pr; if (ph >= 28) ph -= 28;
        }
        s *= (1.0f / 784.0f);
        KRE[t] = s;
        dev = fabsf(s - (t == 0 ? 1.0f : 0.0f));
    }
    #pragma unroll
    for (int m = 32; m >= 1; m >>= 1) dev = fmaxf(dev, __shfl_xor(dev, m, 64));
    if ((t & 63) == 0) atomicMax(&smax, __float_as_int(dev));
    __syncthreads();
    if (t == 0) FLAG[0] = (__int_as_float(smax) < 1e-4f) ? 1.0f : 0.0f;
}

// ---------------------------------------------------------------------------
// Kernel 2: w1_eff[c][k] = sum_q w1[c][q] * kre[(q-k) mod (28,28)], packed into
// MFMA B-fragment order, bf16.  Fast path (delta kernel): w1_eff = w1.
// Packed layout: W1P[(((c>>4)*25 + (k>>5))*64 + l)*8 + e]
//   where l = ((k&31)>>3)<<4 | (c&15), e = k&7  (B[k][col] fragment order).
// ---------------------------------------------------------------------------
__global__ void k_w1pack(const float* __restrict__ W1, const float* __restrict__ KRE,
                         const float* __restrict__ FLAG, u16* __restrict__ W1P)
{
    const int c = blockIdx.x;    // 0..799 (output col / HID idx)
    const int t = threadIdx.x;   // 128
    const bool delta = (FLAG[0] > 0.5f);
    __shared__ float w1d[56 * 56];
    __shared__ float kr[784];

    if (delta) {
        if (t < 100) {
            int k0 = t * 8;
            ushort8v h;
            if (k0 + 7 < NPIX) {
                const float4* wp = (const float4*)(W1 + (size_t)c * NPIX + k0);
                float4 a = wp[0], b = wp[1];
                h[0] = f2bf(a.x); h[1] = f2bf(a.y); h[2] = f2bf(a.z); h[3] = f2bf(a.w);
                h[4] = f2bf(b.x); h[5] = f2bf(b.y); h[6] = f2bf(b.z); h[7] = f2bf(b.w);
            } else {
                #pragma unroll
                for (int e = 0; e < 8; ++e) {
                    int k = k0 + e;
                    h[e] = (k < NPIX) ? f2bf(W1[(size_t)c * NPIX + k]) : (u16)0;
                }
            }
            int kf = k0 >> 5, r = k0 & 31;
            int l  = ((r >> 3) << 4) | (c & 15);
            int nf = c >> 4;
            ((ushort8v*)W1P)[(nf * 25 + kf) * 64 + l] = h;
        }
        return;
    }
    // general mask: explicit circular correlation
    for (int i = t; i < 784; i += 128) kr[i] = KRE[i];
    for (int i = t; i < 3136; i += 128) {
        int r = i / 56, cc = i - r * 56;
        w1d[i] = W1[(size_t)c * NPIX + (r % 28) * 28 + (cc % 28)];
    }
    __syncthreads();
    for (int k = t; k < KP; k += 128) {
        float v = 0.f;
        if (k < NPIX) {
            int krr = k / 28, kcc = k - krr * 28;
            for (int dr = 0; dr < 28; ++dr) {
                const float* wrow = &w1d[(krr + dr) * 56 + kcc];
                const float* krow = &kr[dr * 28];
                #pragma unroll 4
                for (int dc = 0; dc < 28; ++dc) v += wrow[dc] * krow[dc];
            }
        }
        int kf = k >> 5, r = k & 31;
        int l  = ((r >> 3) << 4) | (c & 15);
        int nf = c >> 4;
        W1P[(size_t)(((nf * 25 + kf) * 64 + l) << 3) | (r & 7)] = f2bf(v);
    }
}

// ---------------------------------------------------------------------------
// Kernel 3: fused  h = relu(x @ w1_eff^T + b1);  logits = h @ w4^T + b4;
//                  out = log_softmax(logits)
// 512 blocks x 640 threads (10 waves). BM=64 rows/block, wave w owns cols
// [80w, 80w+80) (5 x 16-col frags, 4 x 16-row frags -> 20 accum frags).
// x staged f32->bf16 into double-buffered LDS (5 stages of K=160).
// ---------------------------------------------------------------------------
#define LDA 168          // padded LDS row stride (bf16 elems): 160 + 8
__global__ __launch_bounds__(640, 3) void k_main(
    const float* __restrict__ X, const u16* __restrict__ W1P,
    const float* __restrict__ B1, const float* __restrict__ W4,
    const float* __restrict__ B4, float* __restrict__ OUT)
{
    __shared__ u16 As[2][64 * LDA];
    __shared__ float PL[10][64][10];

    const int t = threadIdx.x;
    const int row0 = blockIdx.x * 64;
    const int l = t & 63, w = t >> 6;
    const int lc = l & 15, lk = l >> 4;
    const int srow = t / 10, slot = t - srow * 10;
    const float* xrow = X + (size_t)(row0 + srow) * NPIX;

    f32x4 acc[4][5];
    #pragma unroll
    for (int m = 0; m < 4; ++m)
        #pragma unroll
        for (int n = 0; n < 5; ++n) acc[m][n] = (f32x4)(0.0f);

    // ---- stage 0 ----
    {
        int k0 = slot * 16;
        ushort8v h0, h1;
        const float4* p = (const float4*)(xrow + k0);
        float4 a = p[0], b = p[1], c = p[2], d = p[3];
        h0[0]=f2bf(a.x); h0[1]=f2bf(a.y); h0[2]=f2bf(a.z); h0[3]=f2bf(a.w);
        h0[4]=f2bf(b.x); h0[5]=f2bf(b.y); h0[6]=f2bf(b.z); h0[7]=f2bf(b.w);
        h1[0]=f2bf(c.x); h1[1]=f2bf(c.y); h1[2]=f2bf(c.z); h1[3]=f2bf(c.w);
        h1[4]=f2bf(d.x); h1[5]=f2bf(d.y); h1[6]=f2bf(d.z); h1[7]=f2bf(d.w);
        u16* dst = &As[0][srow * LDA + slot * 16];
        *(ushort8v*)dst = h0; *(ushort8v*)(dst + 8) = h1;
    }
    __syncthreads();

    const short8v* BP = (const short8v*)W1P;
    for (int s = 0; s < 5; ++s) {
        const int buf = s & 1;
        if (s < 4) {   // stage s+1 into buf^1 (prev readers of buf^1 done: synced)
            int k0 = (s + 1) * 160 + slot * 16;
            ushort8v h0, h1;
            if (k0 < NPIX) {
                const float4* p = (const float4*)(xrow + k0);
                float4 a = p[0], b = p[1], c = p[2], d = p[3];
                h0[0]=f2bf(a.x); h0[1]=f2bf(a.y); h0[2]=f2bf(a.z); h0[3]=f2bf(a.w);
                h0[4]=f2bf(b.x); h0[5]=f2bf(b.y); h0[6]=f2bf(b.z); h0[7]=f2bf(b.w);
                h1[0]=f2bf(c.x); h1[1]=f2bf(c.y); h1[2]=f2bf(c.z); h1[3]=f2bf(c.w);
                h1[4]=f2bf(d.x); h1[5]=f2bf(d.y); h1[6]=f2bf(d.z); h1[7]=f2bf(d.w);
            } else {
                h0 = (ushort8v)(0); h1 = (ushort8v)(0);
            }
            u16* dst = &As[buf ^ 1][srow * LDA + slot * 16];
            *(ushort8v*)dst = h0; *(ushort8v*)(dst + 8) = h1;
        }
        const u16* abase = &As[buf][lc * LDA + lk * 8];
        #pragma unroll
        for (int kf = 0; kf < 5; ++kf) {
            short8v b[5];
            #pragma unroll
            for (int n = 0; n < 5; ++n)
                b[n] = BP[((w * 5 + n) * 25 + (s * 5 + kf)) * 64 + l];
            #pragma unroll
            for (int m = 0; m < 4; ++m) {
                short8v a = *reinterpret_cast<const short8v*>(abase + m * (16 * LDA) + kf * 32);
                #pragma unroll
                for (int n = 0; n < 5; ++n)
                    acc[m][n] = __builtin_amdgcn_mfma_f32_16x16x32_bf16(a, b[n], acc[m][n], 0, 0, 0);
            }
        }
        __syncthreads();
    }

    // ---- epilogue: bias + relu ----
    #pragma unroll
    for (int n = 0; n < 5; ++n) {
        float bn = B1[w * 80 + n * 16 + lc];
        #pragma unroll
        for (int m = 0; m < 4; ++m)
            #pragma unroll
            for (int j = 0; j < 4; ++j)
                acc[m][n][j] = fmaxf(acc[m][n][j] + bn, 0.0f);
    }
    // ---- logits partials: reduce over this wave's 80 cols ----
    #pragma unroll
    for (int o = 0; o < 10; ++o) {
        float wv[5];
        #pragma unroll
        for (int n = 0; n < 5; ++n) wv[n] = W4[o * NH + w * 80 + n * 16 + lc];
        float p[4][4];
        #pragma unroll
        for (int m = 0; m < 4; ++m)
            #pragma unroll
            for (int j = 0; j < 4; ++j) {
                float s = acc[m][0][j] * wv[0];
                s += acc[m][1][j] * wv[1];
                s += acc[m][2][j] * wv[2];
                s += acc[m][3][j] * wv[3];
                s += acc[m][4][j] * wv[4];
                p[m][j] = s;
            }
        #pragma unroll
        for (int mask = 1; mask <= 8; mask <<= 1)
            #pragma unroll
            for (int m = 0; m < 4; ++m)
                #pragma unroll
                for (int j = 0; j < 4; ++j)
                    p[m][j] += __shfl_xor(p[m][j], mask, 64);
        if (lc == 0) {
            #pragma unroll
            for (int m = 0; m < 4; ++m)
                #pragma unroll
                for (int j = 0; j < 4; ++j)
                    PL[w][m * 16 + lk * 4 + j][o] = p[m][j];
        }
    }
    __syncthreads();
    // ---- cross-wave combine + log_softmax, one row per thread ----
    if (t < 64) {
        float lg[10];
        #pragma unroll
        for (int o = 0; o < 10; ++o) {
            float s = 0.f;
            #pragma unroll
            for (int w2 = 0; w2 < 10; ++w2) s += PL[w2][t][o];
            lg[o] = s + B4[o];
        }
        float mx = lg[0];
        #pragma unroll
        for (int o = 1; o < 10; ++o) mx = fmaxf(mx, lg[o]);
        float se = 0.f;
        #pragma unroll
        for (int o = 0; o < 10; ++o) se += expf(lg[o] - mx);
        float lse = logf(se);
        float* op = OUT + (size_t)(row0 + t) * 10;
        #pragma unroll
        for (int o = 0; o < 10; ++o) op[o] = lg[o] - mx - lse;
    }
}

// ---------------------------------------------------------------------------
extern "C" void kernel_launch(void* const* d_in, const int* in_sizes, int n_in,
                              void* d_out, int out_size, void* d_ws, size_t ws_size,
                              hipStream_t stream)
{
    const float* X   = (const float*)d_in[0];
    const float* MRE = (const float*)d_in[1];
    const float* MIM = (const float*)d_in[2];
    const float* W1  = (const float*)d_in[3];
    const float* B1  = (const float*)d_in[4];
    const float* W4  = (const float*)d_in[5];
    const float* B4  = (const float*)d_in[6];
    float* OUT = (float*)d_out;

    float* kre  = (float*)d_ws;                       // 784 f32
    float* flag = kre + 784;                          // 1 f32
    u16*   w1p  = (u16*)((char*)d_ws + 4096);         // 50*25*64*8 bf16 = 1.28 MB

    k_kre<<<1, 832, 0, stream>>>(MRE, MIM, kre, flag);
    k_w1pack<<<800, 128, 0, stream>>>(W1, kre, flag, w1p);
    k_main<<<512, 640, 0, stream>>>(X, w1p, B1, W4, B4, OUT);
}